// Round 2
// baseline (349.883 us; speedup 1.0000x reference)
//
#include <hip/hip_runtime.h>

// Sinkhorn image loss, scaling-form (no log domain):
//   p = softmax(pred_logits) ; q = target + 1e-8 ; K = exp(-C/eps), eps=0.01
//   a1 = p / (K*1)  (fused with K build) ; then alternate b = q/(K a), a = p/(K b)
//   cost_b = sum_ij a_i b_j K_ij C_ij ; out = mean_b
// f32-safe: K_ii = 1 bounds every row-sum from below.
//
// Layout: 256 blocks x 512 thr (1 block/CU, perfectly balanced).
// Block owns 9 rows x all 16 batches; wave = 9 rows x 2 batches, full j.
// Same 256-block grid for every matvec kernel -> stable block->XCD mapping
// -> each XCD's 288 K rows (2.65 MB) stay resident in its 4 MB L2.

namespace {

constexpr int N  = 2304;                    // 48*48
constexpr int B  = 16;
constexpr int NB = N * B;
constexpr long long NN = (long long)N * N;  // 5,308,416
constexpr int RPB  = 9;                     // rows per block
constexpr int GRID = N / RPB;               // 256

__device__ __forceinline__ float4 expk4(float4 c) {
    float4 k;
    k.x = __expf(c.x * -100.f);
    k.y = __expf(c.y * -100.f);
    k.z = __expf(c.z * -100.f);
    k.w = __expf(c.w * -100.f);
    return k;
}

__device__ __forceinline__ float wave_sum(float v) {
#pragma unroll
    for (int off = 32; off >= 1; off >>= 1) v += __shfl_xor(v, off);
    return v;
}

// ---------------------------------------------------------------- init ----
// One block per batch: P = softmax(logits), Q = target + 1e-8.
__global__ __launch_bounds__(256) void sk_init(const float* __restrict__ logits,
                                               const float* __restrict__ target,
                                               float* __restrict__ P,
                                               float* __restrict__ Q) {
    const int b = blockIdx.x;
    const int t = threadIdx.x;

    float xs[9];
    float m = -3.0e38f;
#pragma unroll
    for (int s = 0; s < 9; ++s) {
        xs[s] = logits[b * N + s * 256 + t];
        m = fmaxf(m, xs[s]);
    }
#pragma unroll
    for (int off = 32; off >= 1; off >>= 1) m = fmaxf(m, __shfl_xor(m, off));

    __shared__ float sm[4], ss[4];
    const int w = t >> 6;
    if ((t & 63) == 0) sm[w] = m;
    __syncthreads();
    m = fmaxf(fmaxf(sm[0], sm[1]), fmaxf(sm[2], sm[3]));

    float sum = 0.f;
#pragma unroll
    for (int s = 0; s < 9; ++s) sum += __expf(xs[s] - m);
#pragma unroll
    for (int off = 32; off >= 1; off >>= 1) sum += __shfl_xor(sum, off);
    if ((t & 63) == 0) ss[w] = sum;
    __syncthreads();
    sum = ss[0] + ss[1] + ss[2] + ss[3];
    const float inv = 1.f / sum;

#pragma unroll
    for (int s = 0; s < 9; ++s) {
        const int i = s * 256 + t;
        P[b * N + i] = __expf(xs[s] - m) * inv;
        Q[b * N + i] = target[b * N + i] + 1e-8f;
    }
}

// --------------------------------------------------- first a-update -------
// K = exp(-100 C) (written by the block that later re-reads it -> XCD-local),
// rowsum accumulated on the fly; A[b][i] = P[b][i] / rowsum_i (b-independent
// since b_hat = 1). Wave w handles row w (wave 0 also row 8), full j.
template <bool WK>
__global__ __launch_bounds__(512, 2) void sk_first(const float* __restrict__ C,
                                                   float* __restrict__ K,
                                                   const float* __restrict__ P,
                                                   float* __restrict__ A) {
    const int i0   = blockIdx.x * RPB;
    const int w    = threadIdx.x >> 6;
    const int lane = threadIdx.x & 63;

    for (int rr = w; rr < RPB; rr += 8) {
        const long long row = (long long)(i0 + rr) * N;
        float s = 0.f;
#pragma unroll
        for (int it = 0; it < 9; ++it) {
            const int j0 = (it * 64 + lane) * 4;
            const float4 k4 = expk4(*(const float4*)(C + row + j0));
            if (WK) *(float4*)(K + row + j0) = k4;
            s += (k4.x + k4.y) + (k4.z + k4.w);
        }
        s = wave_sum(s);
        if (lane < 16) {
            const int idx = lane * N + (i0 + rr);
            A[idx] = P[idx] / s;
        }
    }
}

// ----------------------------------------------------------- half-iter ----
// out[b][i] = src[b][i] / sum_j K[i][j] * win[b][j]
// Wave = 9 rows x 2 batches, j-full (9 iters x 64 lanes x float4).
template <bool UK>
__global__ __launch_bounds__(512, 2) void sk_half(const float* __restrict__ C,
                                                  const float* __restrict__ K,
                                                  const float* __restrict__ src,
                                                  const float* __restrict__ win,
                                                  float* __restrict__ out) {
    const int i0   = blockIdx.x * RPB;
    const int lane = threadIdx.x & 63;
    const int b0   = (threadIdx.x >> 6) * 2;

    float acc[RPB][2];
#pragma unroll
    for (int r = 0; r < RPB; ++r) { acc[r][0] = 0.f; acc[r][1] = 0.f; }

#pragma unroll
    for (int it = 0; it < 9; ++it) {
        const int j0 = (it * 64 + lane) * 4;
        const float4 w0 = *(const float4*)(win + (long long)b0 * N + j0);
        const float4 w1 = *(const float4*)(win + (long long)(b0 + 1) * N + j0);
#pragma unroll
        for (int r = 0; r < RPB; ++r) {
            const long long row = (long long)(i0 + r) * N;
            float4 k4;
            if (UK) k4 = *(const float4*)(K + row + j0);
            else    k4 = expk4(*(const float4*)(C + row + j0));
            acc[r][0] = fmaf(k4.x, w0.x, acc[r][0]);
            acc[r][0] = fmaf(k4.y, w0.y, acc[r][0]);
            acc[r][0] = fmaf(k4.z, w0.z, acc[r][0]);
            acc[r][0] = fmaf(k4.w, w0.w, acc[r][0]);
            acc[r][1] = fmaf(k4.x, w1.x, acc[r][1]);
            acc[r][1] = fmaf(k4.y, w1.y, acc[r][1]);
            acc[r][1] = fmaf(k4.z, w1.z, acc[r][1]);
            acc[r][1] = fmaf(k4.w, w1.w, acc[r][1]);
        }
    }

#pragma unroll
    for (int r = 0; r < RPB; ++r) {
        acc[r][0] = wave_sum(acc[r][0]);
        acc[r][1] = wave_sum(acc[r][1]);
    }

    // select one (row,batch) per lane, then a single parallel division
    float sel = 1.f;
#pragma unroll
    for (int r = 0; r < RPB; ++r) {
        if (lane == r * 2 + 0) sel = acc[r][0];
        if (lane == r * 2 + 1) sel = acc[r][1];
    }
    if (lane < 2 * RPB) {
        const long long idx = (long long)(b0 + (lane & 1)) * N + (i0 + (lane >> 1));
        out[idx] = src[idx] / sel;
    }
}

// --------------------------------------------------------------- final ----
// partial[block] = sum_{r,b} A[b][i] * sum_j (C*K)[i][j] * Bh[b][j]
__global__ __launch_bounds__(512, 2) void sk_final(const float* __restrict__ C,
                                                   const float* __restrict__ A,
                                                   const float* __restrict__ Bh,
                                                   float* __restrict__ partials) {
    const int i0   = blockIdx.x * RPB;
    const int lane = threadIdx.x & 63;
    const int b0   = (threadIdx.x >> 6) * 2;

    float acc[RPB][2];
#pragma unroll
    for (int r = 0; r < RPB; ++r) { acc[r][0] = 0.f; acc[r][1] = 0.f; }

#pragma unroll
    for (int it = 0; it < 9; ++it) {
        const int j0 = (it * 64 + lane) * 4;
        const float4 w0 = *(const float4*)(Bh + (long long)b0 * N + j0);
        const float4 w1 = *(const float4*)(Bh + (long long)(b0 + 1) * N + j0);
#pragma unroll
        for (int r = 0; r < RPB; ++r) {
            const float4 c4 = *(const float4*)(C + (long long)(i0 + r) * N + j0);
            float4 kc;
            kc.x = __expf(c4.x * -100.f) * c4.x;
            kc.y = __expf(c4.y * -100.f) * c4.y;
            kc.z = __expf(c4.z * -100.f) * c4.z;
            kc.w = __expf(c4.w * -100.f) * c4.w;
            acc[r][0] = fmaf(kc.x, w0.x, acc[r][0]);
            acc[r][0] = fmaf(kc.y, w0.y, acc[r][0]);
            acc[r][0] = fmaf(kc.z, w0.z, acc[r][0]);
            acc[r][0] = fmaf(kc.w, w0.w, acc[r][0]);
            acc[r][1] = fmaf(kc.x, w1.x, acc[r][1]);
            acc[r][1] = fmaf(kc.y, w1.y, acc[r][1]);
            acc[r][1] = fmaf(kc.z, w1.z, acc[r][1]);
            acc[r][1] = fmaf(kc.w, w1.w, acc[r][1]);
        }
    }

#pragma unroll
    for (int r = 0; r < RPB; ++r) {
        acc[r][0] = wave_sum(acc[r][0]);
        acc[r][1] = wave_sum(acc[r][1]);
    }

    float prod = 0.f;
#pragma unroll
    for (int r = 0; r < RPB; ++r) {
        if (lane == r * 2 + 0) prod = acc[r][0];
        if (lane == r * 2 + 1) prod = acc[r][1];
    }
    if (lane < 2 * RPB) {
        prod *= A[(long long)(b0 + (lane & 1)) * N + (i0 + (lane >> 1))];
    } else {
        prod = 0.f;
    }
    prod = wave_sum(prod);

    __shared__ float sred[8];
    if (lane == 0) sred[threadIdx.x >> 6] = prod;
    __syncthreads();
    if (threadIdx.x == 0) {
        float t = 0.f;
#pragma unroll
        for (int i = 0; i < 8; ++i) t += sred[i];
        partials[blockIdx.x] = t;
    }
}

// -------------------------------------------------------------- reduce ----
__global__ __launch_bounds__(256) void sk_reduce(const float* __restrict__ partials,
                                                 float* __restrict__ out) {
    float v = partials[threadIdx.x];  // exactly 256 partials
    v = wave_sum(v);
    __shared__ float s[4];
    if ((threadIdx.x & 63) == 0) s[threadIdx.x >> 6] = v;
    __syncthreads();
    if (threadIdx.x == 0) out[0] = (s[0] + s[1] + s[2] + s[3]) * (1.f / 16.f);
}

}  // namespace

extern "C" void kernel_launch(void* const* d_in, const int* in_sizes, int n_in,
                              void* d_out, int out_size, void* d_ws, size_t ws_size,
                              hipStream_t stream) {
    const float* logits = (const float*)d_in[0];   // (B, 48, 48)
    const float* target = (const float*)d_in[1];   // (B, 48, 48)
    const float* C      = (const float*)d_in[2];   // (1, N, N)
    float* out = (float*)d_out;
    float* ws  = (float*)d_ws;

    float* partials = ws;             // [256]
    float* A  = ws + 256;             // [B][N] a-hat
    float* Bh = A + NB;               // [B][N] b-hat
    float* P  = Bh + NB;              // [B][N]
    float* Q  = P + NB;               // [B][N]
    float* K  = Q + NB;               // [N][N] (optional)

    const bool use_k =
        ws_size >= ((size_t)(256 + 4 * NB) + (size_t)NN) * sizeof(float);

    sk_init<<<B, 256, 0, stream>>>(logits, target, P, Q);

    if (use_k) {
        sk_first<true><<<GRID, 512, 0, stream>>>(C, K, P, A);     // a1
        sk_half<true><<<GRID, 512, 0, stream>>>(C, K, Q, A, Bh);  // b1
        for (int t = 1; t < 10; ++t) {
            sk_half<true><<<GRID, 512, 0, stream>>>(C, K, P, Bh, A);
            sk_half<true><<<GRID, 512, 0, stream>>>(C, K, Q, A, Bh);
        }
    } else {
        sk_first<false><<<GRID, 512, 0, stream>>>(C, K, P, A);
        sk_half<false><<<GRID, 512, 0, stream>>>(C, K, Q, A, Bh);
        for (int t = 1; t < 10; ++t) {
            sk_half<false><<<GRID, 512, 0, stream>>>(C, K, P, Bh, A);
            sk_half<false><<<GRID, 512, 0, stream>>>(C, K, Q, A, Bh);
        }
    }

    sk_final<<<GRID, 512, 0, stream>>>(C, A, Bh, partials);
    sk_reduce<<<1, 256, 0, stream>>>(partials, out);
}

// Round 3
// 199.342 us; speedup vs baseline: 1.7552x; 1.7552x over previous
//
#include <hip/hip_runtime.h>

// Sinkhorn image loss, scaling-form (no log domain):
//   p = softmax(pred_logits) ; q = target + 1e-8 ; K = exp(-C/eps), eps=0.01
//   a1 = p / rowsum(K) (fused with K build); alternate b = q/(K a), a = p/(K b)
//   cost_b = sum_ij a_i b_j K_ij C_ij ; out = mean_b
// f32-safe: K_ii = 1 bounds every row-sum from below.
//
// Matvec shape: wave = 6 rows x 8 batches x full-j. 768 one-wave blocks
// (= 3 blocks/CU exactly, no tail). Per j-step: 14 float4 loads vs 192 FMAs
// (384 VALU cyc) -> latency hidden by 2-deep register double-buffer.
// bid -> (g = bid % 384, h = bid / 384): both b-half readers of a K row share
// the XCD (bid%8 == g%8) with its sk_first writer; 2.65 MB K/XCD stays in L2.

namespace {

constexpr int N  = 2304;                    // 48*48
constexpr int B  = 16;
constexpr int NB = N * B;
constexpr long long NN = (long long)N * N;  // 5,308,416

__device__ __forceinline__ float4 expk4(float4 c) {
    float4 k;
    k.x = __expf(c.x * -100.f);
    k.y = __expf(c.y * -100.f);
    k.z = __expf(c.z * -100.f);
    k.w = __expf(c.w * -100.f);
    return k;
}

__device__ __forceinline__ float wave_sum(float v) {
#pragma unroll
    for (int off = 32; off >= 1; off >>= 1) v += __shfl_xor(v, off);
    return v;
}

// Fold-reduce: NV values/lane -> NV/2, consuming lane bit `bit`.
// After folding bits 1,2,4,8: slot k on lane l holds full 16-lane-group sum
// of original index 16k + (l & 15).
template <int NV>
__device__ __forceinline__ void fold(float* v, int bit) {
    const bool hi = (threadIdx.x & bit) != 0;
#pragma unroll
    for (int k = 0; k < NV / 2; ++k) {
        const float a = hi ? v[2 * k + 1] : v[2 * k];
        const float b = hi ? v[2 * k]     : v[2 * k + 1];
        v[k] = a + __shfl_xor(b, bit);
    }
}

// ---------------------------------------------------------------- init ----
// One block per batch: P = softmax(logits), Q = target + 1e-8.
__global__ __launch_bounds__(256) void sk_init(const float* __restrict__ logits,
                                               const float* __restrict__ target,
                                               float* __restrict__ P,
                                               float* __restrict__ Q) {
    const int b = blockIdx.x;
    const int t = threadIdx.x;

    float xs[9];
    float m = -3.0e38f;
#pragma unroll
    for (int s = 0; s < 9; ++s) {
        xs[s] = logits[b * N + s * 256 + t];
        m = fmaxf(m, xs[s]);
    }
#pragma unroll
    for (int off = 32; off >= 1; off >>= 1) m = fmaxf(m, __shfl_xor(m, off));

    __shared__ float sm[4], ss[4];
    const int w = t >> 6;
    if ((t & 63) == 0) sm[w] = m;
    __syncthreads();
    m = fmaxf(fmaxf(sm[0], sm[1]), fmaxf(sm[2], sm[3]));

    float sum = 0.f;
#pragma unroll
    for (int s = 0; s < 9; ++s) sum += __expf(xs[s] - m);
#pragma unroll
    for (int off = 32; off >= 1; off >>= 1) sum += __shfl_xor(sum, off);
    if ((t & 63) == 0) ss[w] = sum;
    __syncthreads();
    sum = ss[0] + ss[1] + ss[2] + ss[3];
    const float inv = 1.f / sum;

#pragma unroll
    for (int s = 0; s < 9; ++s) {
        const int i = s * 256 + t;
        P[b * N + i] = __expf(xs[s] - m) * inv;
        Q[b * N + i] = target[b * N + i] + 1e-8f;
    }
}

// --------------------------------------------------- first a-update -------
// 384 one-wave blocks x 6 rows: K = exp(-100C) written by the XCD that will
// re-read it; rowsums on the fly; A[b][i] = P[b][i]/rowsum_i for all 16 b.
template <bool WK>
__global__ __launch_bounds__(64) void sk_first(const float* __restrict__ C,
                                               float* __restrict__ K,
                                               const float* __restrict__ P,
                                               float* __restrict__ A) {
    const int i0   = blockIdx.x * 6;
    const int lane = threadIdx.x;
    const int jl   = lane * 4;

    float s[6];
#pragma unroll
    for (int r = 0; r < 6; ++r) s[r] = 0.f;

#pragma unroll
    for (int it = 0; it < 9; ++it) {
        const int j0 = it * 256 + jl;
#pragma unroll
        for (int r = 0; r < 6; ++r) {
            const int off = (i0 + r) * N + j0;
            const float4 k4 = expk4(*(const float4*)(C + off));
            if (WK) *(float4*)(K + off) = k4;
            s[r] += (k4.x + k4.y) + (k4.z + k4.w);
        }
    }
#pragma unroll
    for (int r = 0; r < 6; ++r) s[r] = wave_sum(s[r]);

    if (lane < B) {
#pragma unroll
        for (int r = 0; r < 6; ++r) {
            const int idx = lane * N + (i0 + r);
            A[idx] = P[idx] / s[r];
        }
    }
}

// ----------------------------------------------------------- half-iter ----
// out[b][i] = src[b][i] / sum_j K[i][j] * win[b][j]
// 768 one-wave blocks; wave = 6 rows x 8 batches x full-j.
template <bool UK>
__global__ __launch_bounds__(64) void sk_half(const float* __restrict__ C,
                                              const float* __restrict__ K,
                                              const float* __restrict__ src,
                                              const float* __restrict__ win,
                                              float* __restrict__ out) {
    const int bid = blockIdx.x;
    const int h   = bid >= 384 ? 1 : 0;
    const int g   = bid - (h ? 384 : 0);
    const int i0  = g * 6;
    const int b0  = h * 8;
    const int lane = threadIdx.x;
    const int jl   = lane * 4;

    const float* __restrict__ Kb = UK ? K : C;

    float v[48];
#pragma unroll
    for (int k = 0; k < 48; ++k) v[k] = 0.f;

    float4 kb[2][6], wb[2][8];
#pragma unroll
    for (int r = 0; r < 6; ++r) kb[0][r] = *(const float4*)(Kb + (i0 + r) * N + jl);
#pragma unroll
    for (int bb = 0; bb < 8; ++bb) wb[0][bb] = *(const float4*)(win + (b0 + bb) * N + jl);

#pragma unroll
    for (int it = 0; it < 9; ++it) {
        const int cur = it & 1, nxt = cur ^ 1;
        if (it < 8) {  // compile-time after unroll
            const int j0 = (it + 1) * 256 + jl;
#pragma unroll
            for (int r = 0; r < 6; ++r)
                kb[nxt][r] = *(const float4*)(Kb + (i0 + r) * N + j0);
#pragma unroll
            for (int bb = 0; bb < 8; ++bb)
                wb[nxt][bb] = *(const float4*)(win + (b0 + bb) * N + j0);
        }
#pragma unroll
        for (int r = 0; r < 6; ++r) {
            float4 k4 = kb[cur][r];
            if (!UK) k4 = expk4(k4);
#pragma unroll
            for (int bb = 0; bb < 8; ++bb) {
                const float4 w4 = wb[cur][bb];
                float& a = v[r * 8 + bb];
                a = fmaf(k4.x, w4.x, a);
                a = fmaf(k4.y, w4.y, a);
                a = fmaf(k4.z, w4.z, a);
                a = fmaf(k4.w, w4.w, a);
            }
        }
    }

    fold<48>(v, 1);
    fold<24>(v, 2);
    fold<12>(v, 4);
    fold<6>(v, 8);
#pragma unroll
    for (int k = 0; k < 3; ++k) {
        v[k] += __shfl_xor(v[k], 16);
        v[k] += __shfl_xor(v[k], 32);
    }

    if (lane < 16) {
        const int bb  = lane & 7;
        const int rhi = lane >> 3;
#pragma unroll
        for (int k = 0; k < 3; ++k) {
            const int r   = 2 * k + rhi;
            const int idx = (b0 + bb) * N + (i0 + r);
            out[idx] = src[idx] / v[k];
        }
    }
}

// --------------------------------------------------------------- final ----
// partial[bid] = sum_{6 rows, 8 b} A[b][i] * sum_j C*K[i][j] * Bh[b][j]
__global__ __launch_bounds__(64) void sk_final(const float* __restrict__ C,
                                               const float* __restrict__ A,
                                               const float* __restrict__ Bh,
                                               float* __restrict__ partials) {
    const int bid = blockIdx.x;
    const int h   = bid >= 384 ? 1 : 0;
    const int g   = bid - (h ? 384 : 0);
    const int i0  = g * 6;
    const int b0  = h * 8;
    const int lane = threadIdx.x;
    const int jl   = lane * 4;

    float v[48];
#pragma unroll
    for (int k = 0; k < 48; ++k) v[k] = 0.f;

#pragma unroll
    for (int it = 0; it < 9; ++it) {
        const int j0 = it * 256 + jl;
        float4 wv[8];
#pragma unroll
        for (int bb = 0; bb < 8; ++bb)
            wv[bb] = *(const float4*)(Bh + (b0 + bb) * N + j0);
#pragma unroll
        for (int r = 0; r < 6; ++r) {
            const float4 c4 = *(const float4*)(C + (i0 + r) * N + j0);
            float4 kc;
            kc.x = __expf(c4.x * -100.f) * c4.x;
            kc.y = __expf(c4.y * -100.f) * c4.y;
            kc.z = __expf(c4.z * -100.f) * c4.z;
            kc.w = __expf(c4.w * -100.f) * c4.w;
#pragma unroll
            for (int bb = 0; bb < 8; ++bb) {
                float& a = v[r * 8 + bb];
                a = fmaf(kc.x, wv[bb].x, a);
                a = fmaf(kc.y, wv[bb].y, a);
                a = fmaf(kc.z, wv[bb].z, a);
                a = fmaf(kc.w, wv[bb].w, a);
            }
        }
    }

    fold<48>(v, 1);
    fold<24>(v, 2);
    fold<12>(v, 4);
    fold<6>(v, 8);
#pragma unroll
    for (int k = 0; k < 3; ++k) {
        v[k] += __shfl_xor(v[k], 16);
        v[k] += __shfl_xor(v[k], 32);
    }

    // every 16-lane group holds identical sums -> 4x duplication, scale 1/4
    const int bb  = lane & 7;
    const int rhi = (lane >> 3) & 1;
    float val = 0.f;
#pragma unroll
    for (int k = 0; k < 3; ++k) {
        const int r = 2 * k + rhi;
        val += v[k] * A[(b0 + bb) * N + (i0 + r)];
    }
    val = wave_sum(val) * 0.25f;
    if (lane == 0) partials[bid] = val;
}

// -------------------------------------------------------------- reduce ----
__global__ __launch_bounds__(256) void sk_reduce(const float* __restrict__ partials,
                                                 float* __restrict__ out) {
    const int t = threadIdx.x;
    float v = partials[t] + partials[t + 256] + partials[t + 512];
    v = wave_sum(v);
    __shared__ float s[4];
    if ((t & 63) == 0) s[t >> 6] = v;
    __syncthreads();
    if (t == 0) out[0] = (s[0] + s[1] + s[2] + s[3]) * (1.f / 16.f);
}

}  // namespace

extern "C" void kernel_launch(void* const* d_in, const int* in_sizes, int n_in,
                              void* d_out, int out_size, void* d_ws, size_t ws_size,
                              hipStream_t stream) {
    const float* logits = (const float*)d_in[0];   // (B, 48, 48)
    const float* target = (const float*)d_in[1];   // (B, 48, 48)
    const float* C      = (const float*)d_in[2];   // (1, N, N)
    float* out = (float*)d_out;
    float* ws  = (float*)d_ws;

    float* partials = ws;             // [768]
    float* A  = ws + 768;             // [B][N] a-hat
    float* Bh = A + NB;               // [B][N] b-hat
    float* P  = Bh + NB;              // [B][N]
    float* Q  = P + NB;               // [B][N]
    float* K  = Q + NB;               // [N][N] (optional)

    const bool use_k =
        ws_size >= ((size_t)(768 + 4 * NB) + (size_t)NN) * sizeof(float);

    sk_init<<<B, 256, 0, stream>>>(logits, target, P, Q);

    if (use_k) {
        sk_first<true><<<384, 64, 0, stream>>>(C, K, P, A);      // a1 (+K build)
        sk_half<true><<<768, 64, 0, stream>>>(C, K, Q, A, Bh);   // b1
        for (int t = 1; t < 10; ++t) {
            sk_half<true><<<768, 64, 0, stream>>>(C, K, P, Bh, A);
            sk_half<true><<<768, 64, 0, stream>>>(C, K, Q, A, Bh);
        }
    } else {
        sk_first<false><<<384, 64, 0, stream>>>(C, K, P, A);
        sk_half<false><<<768, 64, 0, stream>>>(C, K, Q, A, Bh);
        for (int t = 1; t < 10; ++t) {
            sk_half<false><<<768, 64, 0, stream>>>(C, K, P, Bh, A);
            sk_half<false><<<768, 64, 0, stream>>>(C, K, Q, A, Bh);
        }
    }

    sk_final<<<768, 64, 0, stream>>>(C, A, Bh, partials);
    sk_reduce<<<1, 256, 0, stream>>>(partials, out);
}